// Round 6
// baseline (30.085 us; speedup 1.0000x reference)
//
#include <hip/hip_runtime.h>

// Volume rendering: M=65536 rays, N=128 samples/ray.
// Round-6: software-pipelined persistent waves.
//  - 16 lanes/ray, 8 samples/lane (all loads dwordx4), no LDS.
//  - Each block processes 64 rays in NITER=4 unrolled iterations of 16 rays;
//    iteration k+1's 10 global loads are issued BEFORE iteration k's compute,
//    so ~160B/lane stays in flight under the serial scan/exp/reduce chain.
//
// NOTE: exclusive scan MUST be shfl_up(inclusive, 1), not (inclusive - local):
// the terminal tau = density*1e10 (~2e10) absorbs the finite prefix in fp32.

#define NSAMP 128
#define NITER 4
#define RAYS_PER_ITER_BLOCK 16            // 256 threads / 16 lanes per ray
#define RAYS_PER_BLOCK (RAYS_PER_ITER_BLOCK * NITER)   // 64

struct RayData {
    float4 da, db, sa, sb;                // depth, density (8 samples)
    float4 f0, f1, f2, f3, f4, f5;        // feature (8 samples x rgb)
};

__device__ __forceinline__ RayData load_ray(
    const float* __restrict__ density,
    const float* __restrict__ feature,
    const float* __restrict__ depth,
    int ray, int sub)
{
    RayData R;
    const int s0 = 8 * sub;
    const size_t rowN = (size_t)ray * NSAMP;
    R.da = *(const float4*)(depth   + rowN + s0);
    R.db = *(const float4*)(depth   + rowN + s0 + 4);
    R.sa = *(const float4*)(density + rowN + s0);
    R.sb = *(const float4*)(density + rowN + s0 + 4);
    const float* fbase = feature + (size_t)ray * (NSAMP * 3) + (size_t)s0 * 3;
    R.f0 = *(const float4*)(fbase + 0);
    R.f1 = *(const float4*)(fbase + 4);
    R.f2 = *(const float4*)(fbase + 8);
    R.f3 = *(const float4*)(fbase + 12);
    R.f4 = *(const float4*)(fbase + 16);
    R.f5 = *(const float4*)(fbase + 20);
    return R;
}

__device__ __forceinline__ void compute_ray(
    const RayData& R, int ray, int sub, float* __restrict__ out)
{
    // ---- deltas (terminal delta = 1e10) ----
    float nx = __shfl_down(R.da.x, 1, 16);     // depth[s0+8] from next lane
    float t0 = R.sa.x * (R.da.y - R.da.x);
    float t1 = R.sa.y * (R.da.z - R.da.y);
    float t2 = R.sa.z * (R.da.w - R.da.z);
    float t3 = R.sa.w * (R.db.x - R.da.w);
    float t4 = R.sb.x * (R.db.y - R.db.x);
    float t5 = R.sb.y * (R.db.z - R.db.y);
    float t6 = R.sb.z * (R.db.w - R.db.z);
    float t7 = R.sb.w * ((sub == 15) ? 1e10f : (nx - R.db.w));

    float psum = ((t0 + t1) + (t2 + t3)) + ((t4 + t5) + (t6 + t7));

    // ---- inclusive segmented scan (width 16, 4 steps) ----
    float v = psum;
    #pragma unroll
    for (int off = 1; off < 16; off <<= 1) {
        float t = __shfl_up(v, off, 16);
        if (sub >= off) v += t;
    }
    float excl = __shfl_up(v, 1, 16);          // exact exclusive scan
    if (sub == 0) excl = 0.0f;

    float c0 = excl;
    float c1 = c0 + t0;
    float c2 = c1 + t1;
    float c3 = c2 + t2;
    float c4 = c3 + t3;
    float c5 = c4 + t4;
    float c6 = c5 + t5;
    float c7 = c6 + t6;
    float c8 = c7 + t7;                        // lane 15: huge -> T8 = 0 exactly
    float T0 = __expf(-c0), T1 = __expf(-c1), T2 = __expf(-c2);
    float T3 = __expf(-c3), T4 = __expf(-c4), T5 = __expf(-c5);
    float T6 = __expf(-c6), T7 = __expf(-c7), T8 = __expf(-c8);
    float w0 = T0 - T1, w1 = T1 - T2, w2 = T2 - T3, w3 = T3 - T4;
    float w4 = T4 - T5, w5 = T5 - T6, w6 = T6 - T7, w7 = T7 - T8;

    // ---- weighted accumulation (8 samples) ----
    float r  = w0*R.f0.x + w1*R.f0.w + w2*R.f1.z + w3*R.f2.y
             + w4*R.f3.x + w5*R.f3.w + w6*R.f4.z + w7*R.f5.y;
    float g  = w0*R.f0.y + w1*R.f1.x + w2*R.f1.w + w3*R.f2.z
             + w4*R.f3.y + w5*R.f4.x + w6*R.f4.w + w7*R.f5.z;
    float b  = w0*R.f0.z + w1*R.f1.y + w2*R.f2.x + w3*R.f2.w
             + w4*R.f3.z + w5*R.f4.y + w6*R.f5.x + w7*R.f5.w;
    float dd = w0*R.da.x + w1*R.da.y + w2*R.da.z + w3*R.da.w
             + w4*R.db.x + w5*R.db.y + w6*R.db.z + w7*R.db.w;

    // ---- segmented reduction (width 16, 4 steps) ----
    #pragma unroll
    for (int off = 8; off >= 1; off >>= 1) {
        r  += __shfl_down(r,  off, 16);
        g  += __shfl_down(g,  off, 16);
        b  += __shfl_down(b,  off, 16);
        dd += __shfl_down(dd, off, 16);
    }

    if (sub == 0) {
        *(float4*)(out + (size_t)ray * 4) = make_float4(r, g, b, dd);
    }
}

__global__ __launch_bounds__(256) void volrend_kernel(
    const float* __restrict__ density,   // [M,N]
    const float* __restrict__ feature,   // [M,N,3]
    const float* __restrict__ depth,     // [M,N]
    float* __restrict__ out,             // [M,4]
    int M)
{
    const int sub   = threadIdx.x & 15;
    const int rslot = threadIdx.x >> 4;              // 0..15 within block
    const int ray_base = blockIdx.x * RAYS_PER_BLOCK + rslot;
    // iteration k handles ray_base + k*16 (block's 64 rays are contiguous)

    // prologue: issue iteration 0's loads
    RayData cur = load_ray(density, feature, depth, ray_base, sub);

    #pragma unroll
    for (int k = 0; k < NITER; ++k) {
        RayData nxt;
        if (k + 1 < NITER) {
            // issue next iteration's loads BEFORE consuming cur -> they stay
            // in flight under the scan/exp/reduce chain below.
            nxt = load_ray(density, feature, depth,
                           ray_base + (k + 1) * RAYS_PER_ITER_BLOCK, sub);
        }
        compute_ray(cur, ray_base + k * RAYS_PER_ITER_BLOCK, sub, out);
        if (k + 1 < NITER) cur = nxt;
    }
}

extern "C" void kernel_launch(void* const* d_in, const int* in_sizes, int n_in,
                              void* d_out, int out_size, void* d_ws, size_t ws_size,
                              hipStream_t stream) {
    const float* density = (const float*)d_in[0];   // [M,N,1]
    const float* feature = (const float*)d_in[1];   // [M,N,3]
    const float* depth   = (const float*)d_in[2];   // [M,N]
    float* out = (float*)d_out;

    const int M = in_sizes[2] / NSAMP;              // 65536 (divisible by 64)

    const int threads = 256;
    const int blocks = M / RAYS_PER_BLOCK;          // 1024
    volrend_kernel<<<blocks, threads, 0, stream>>>(density, feature, depth, out, M);
}